// Round 9
// baseline (158.896 us; speedup 1.0000x reference)
//
#include <hip/hip_runtime.h>
#include <stdint.h>

#define NTREES 8
#define NNODES 5
#define CC 16
#define BB 8
#define HH 224
#define WW 224

struct Forest { int par[NTREES * NNODES]; };

// Plan: per-(b,c) union of distinct DP chains across the realized forest,
// plus one root formula per distinct tree class.
// chain i (i>=1): v_i = fv * s_L^eL[i] * s_{src[i]}^eS[i]   (chain 0 = L: v=fv)
// root r:         v0  = fv * s_L^rRL[r] * s_{rIdx[r]}^rExp[r]   (rN[r]=0 -> no extra)
// rTrees[r]: bitmask of trees with this class (out = exp(asum_t)*m_r - 1).
struct Plan {
  int nw, nchains, nroots;
  int eL[8], src[8], eS[8];
  int rRL[8], rN[8], rIdx[8], rExp[8], rTrees[8];
};

// ---------------------------------------------------------------------------
// Host-side bit-exact reproduction of np.random.default_rng(0) forest
// (verified absmax 0.0 vs numpy in rounds 1-8 — do not touch).
// ---------------------------------------------------------------------------
namespace nprng {

struct Pcg {
  __uint128_t state, inc;
  int has_uint32;
  uint32_t uinteger;
};

static inline __uint128_t pcg_mult() {
  return (((__uint128_t)0x2360ED051FC65DA4ULL) << 64) | 0x4385DF649FCCF645ULL;
}

static inline void pcg_step(Pcg& s) { s.state = s.state * pcg_mult() + s.inc; }

static inline uint64_t pcg_next64(Pcg& s) {
  pcg_step(s);
  uint64_t xored = (uint64_t)(s.state >> 64) ^ (uint64_t)s.state;
  unsigned rot = (unsigned)(s.state >> 122);
  return (xored >> rot) | (xored << ((64u - rot) & 63u));
}

static inline uint32_t pcg_next32(Pcg& s) {
  if (s.has_uint32) { s.has_uint32 = 0; return s.uinteger; }
  uint64_t n = pcg_next64(s);
  s.has_uint32 = 1;
  s.uinteger = (uint32_t)(n >> 32);
  return (uint32_t)n;
}

static inline uint32_t lemire32(Pcg& s, uint32_t rng) {
  const uint32_t rng_excl = rng + 1u;
  uint64_t m = (uint64_t)pcg_next32(s) * (uint64_t)rng_excl;
  uint32_t leftover = (uint32_t)m;
  if (leftover < rng_excl) {
    const uint32_t threshold = (uint32_t)((0xFFFFFFFFu - rng) % rng_excl);
    while (leftover < threshold) {
      m = (uint64_t)pcg_next32(s) * (uint64_t)rng_excl;
      leftover = (uint32_t)m;
    }
  }
  return (uint32_t)(m >> 32);
}

static void make_forest(Forest& f) {
  const uint32_t INIT_A = 0x43b0d7e5u, MULT_A = 0x931e8875u;
  const uint32_t INIT_B = 0x8b51f9ddu, MULT_B = 0x58f38dedu;
  const uint32_t MIX_L  = 0xca01f9ddu, MIX_R  = 0x4973f715u;
  uint32_t pool[4];
  uint32_t hc = INIT_A;
  auto hashmix = [&](uint32_t v) -> uint32_t {
    v ^= hc; hc *= MULT_A; v *= hc; v ^= v >> 16; return v;
  };
  auto mix = [&](uint32_t x, uint32_t y) -> uint32_t {
    uint32_t r = MIX_L * x - MIX_R * y; r ^= r >> 16; return r;
  };
  pool[0] = hashmix(0u);
  for (int i = 1; i < 4; ++i) pool[i] = hashmix(0u);
  for (int is = 0; is < 4; ++is)
    for (int id = 0; id < 4; ++id)
      if (is != id) pool[id] = mix(pool[id], hashmix(pool[is]));
  uint32_t st32[8];
  uint32_t hb = INIT_B;
  for (int i = 0; i < 8; ++i) {
    uint32_t dv = pool[i & 3];
    dv ^= hb; hb *= MULT_B; dv *= hb; dv ^= dv >> 16;
    st32[i] = dv;
  }
  uint64_t w64[4];
  for (int i = 0; i < 4; ++i)
    w64[i] = (uint64_t)st32[2 * i] | ((uint64_t)st32[2 * i + 1] << 32);

  __uint128_t initstate = (((__uint128_t)w64[0]) << 64) | w64[1];
  __uint128_t initseq   = (((__uint128_t)w64[2]) << 64) | w64[3];
  Pcg s;
  s.state = 0; s.inc = (initseq << 1) | 1;
  pcg_step(s);
  s.state += initstate;
  pcg_step(s);
  s.has_uint32 = 0; s.uinteger = 0;

  for (int t = 0; t < NTREES; ++t) {
    f.par[t * NNODES + 0] = -1;
    for (int i = 1; i < NNODES; ++i) {
      uint32_t rng = (uint32_t)(i - 1);
      f.par[t * NNODES + i] = (rng == 0) ? 0 : (int)lemire32(s, rng);
    }
  }
}

}  // namespace nprng

// ---------------------------------------------------------------------------
// Tree-shape classification (verified via absmax 0.0 in R8). Classes:
//  c1 {L,L,L,L}      c2 {I(L),L,L}    c3 {I(LL),L}   c4 {I(LLL)}  c5 {I(L),I(L)}
//  c6 {I(I(L)),L}    c7 {I(I(L),L)}   c9 {I(I(LL))}  c8 {I(I(I(L)))}
// ---------------------------------------------------------------------------
static int classify_tree(const int* p) {
  int nch[NNODES] = {0, 0, 0, 0, 0};
  for (int i = 1; i < NNODES; ++i) nch[p[i]]++;
  int internals[3], nI = 0;
  for (int i = 1; i <= 3; ++i) if (nch[i] > 0) internals[nI++] = i;
  if (nI == 0) return 1;
  if (nI == 1) {
    int m = nch[internals[0]];
    return m == 1 ? 2 : (m == 2 ? 3 : 4);
  }
  if (nI == 2) {
    int i = internals[0], j = internals[1];
    if (p[j] == i) {
      if (nch[j] == 2) return 9;
      return (nch[i] - 1 == 1) ? 7 : 6;
    }
    return 5;
  }
  return 8;
}

// Chain/root formulas per class (same exponents as R8's verified Cfg<>).
static void build_plan(const Forest& f, Plan& p) {
  int cls[NTREES];
  for (int t = 0; t < NTREES; ++t) cls[t] = classify_tree(&f.par[t * NNODES]);

  p.nchains = 1;                       // chain 0 = L (v = fv)
  p.eL[0] = 0; p.src[0] = -1; p.eS[0] = 0;
  p.nroots = 0;
  int rCls[8];

  auto addChain = [&](int eL, int src, int eS) -> int {
    for (int i = 1; i < p.nchains; ++i)
      if (p.eL[i] == eL && p.src[i] == src && p.eS[i] == eS) return i;
    int i = p.nchains++;
    p.eL[i] = eL; p.src[i] = src; p.eS[i] = eS;
    return i;
  };

  for (int t = 0; t < NTREES; ++t) {
    int cl = cls[t], r = -1;
    for (int j = 0; j < p.nroots; ++j) if (rCls[j] == cl) { r = j; break; }
    if (r >= 0) { p.rTrees[r] |= 1 << t; continue; }
    r = p.nroots++;
    rCls[r] = cl; p.rTrees[r] = 1 << t;
    int RL = 0, N = 1, idx = 0, ex = 1;
    switch (cl) {
      case 1: RL = 4; N = 0; break;
      case 2: idx = addChain(1, -1, 0); RL = 2; break;
      case 3: idx = addChain(2, -1, 0); RL = 1; break;
      case 4: idx = addChain(3, -1, 0); break;
      case 5: idx = addChain(1, -1, 0); ex = 2; break;
      case 6: { int a = addChain(1, -1, 0); idx = addChain(0, a, 1); RL = 1; } break;
      case 7: { int a = addChain(1, -1, 0); idx = addChain(1, a, 1); } break;
      case 8: { int a = addChain(1, -1, 0); int bb = addChain(0, a, 1);
                idx = addChain(0, bb, 1); } break;
      case 9: { int a = addChain(2, -1, 0); idx = addChain(0, a, 1); } break;
    }
    p.rRL[r] = RL; p.rN[r] = N; p.rIdx[r] = idx; p.rExp[r] = ex;
  }
  for (int i = p.nchains; i < 8; ++i) { p.eL[i] = 0; p.src[i] = -1; p.eS[i] = 0; }
  for (int i = p.nroots; i < 8; ++i) {
    p.rRL[i] = 0; p.rN[i] = 0; p.rIdx[i] = 0; p.rExp[i] = 1; p.rTrees[i] = 0;
  }
  p.nw = (p.nchains > p.nroots) ? p.nchains : p.nroots;
}

// ---------------------------------------------------------------------------
// DPP helpers (product space, max identity 0.0; semantics verified R4-R8).
// scan64: 6-stage inclusive 64-lane max-scan, single asm block, s_nop 1
// between dependent same-register DPP ops (2 wait states).
// ---------------------------------------------------------------------------
__device__ __forceinline__ float wshr1(float t) {
  int r = __builtin_amdgcn_update_dpp(
      0, __builtin_bit_cast(int, t), 0x138, 0xf, 0xf, true);  // wave_shr:1
  return __builtin_bit_cast(float, r);
}

__device__ __forceinline__ float scan64(float q) {
  asm volatile(
      "s_nop 1\n\t"
      "v_max_f32_dpp %0, %0, %0 row_shr:1 row_mask:0xf bank_mask:0xf\n\t"
      "s_nop 1\n\t"
      "v_max_f32_dpp %0, %0, %0 row_shr:2 row_mask:0xf bank_mask:0xf\n\t"
      "s_nop 1\n\t"
      "v_max_f32_dpp %0, %0, %0 row_shr:4 row_mask:0xf bank_mask:0xf\n\t"
      "s_nop 1\n\t"
      "v_max_f32_dpp %0, %0, %0 row_shr:8 row_mask:0xf bank_mask:0xf\n\t"
      "s_nop 1\n\t"
      "v_max_f32_dpp %0, %0, %0 row_bcast:15 row_mask:0xa bank_mask:0xf\n\t"
      "s_nop 1\n\t"
      "v_max_f32_dpp %0, %0, %0 row_bcast:31 row_mask:0xc bank_mask:0xf\n\t"
      "s_nop 1"
      : "+v"(q));
  return q;
}

#define MUL4(d, s) { (d).x *= (s).x; (d).y *= (s).y; (d).z *= (s).z; (d).w *= (s).w; }
#define MAX4(d, s) { (d).x = fmaxf((d).x,(s).x); (d).y = fmaxf((d).y,(s).y); \
                     (d).z = fmaxf((d).z,(s).z); (d).w = fmaxf((d).w,(s).w); }

// LDS slot layout per (parity, chain): 272 floats; [0..3]=0 (idx 3 = lane-0
// border sentinel), lane data (pm float4) at [4+4*lane] (16B-aligned).
// s(w)=M(h-1,w-1): s.x = prev lane's pm.w = slot[3+4*lane]; s.yzw = pm.xyz.
#define SLOTF 272
#define CH_MAX 8

__device__ __forceinline__ float4 read_s(const float* slot, int lane) {
  float4 pmv = *(const float4*)(slot + 4 + lane * 4);  // ds_read_b128
  float  bx  = slot[3 + lane * 4];                     // ds_read_b32
  return make_float4(bx, pmv.x, pmv.y, pmv.z);
}

// ---------------------------------------------------------------------------
// One block per (b,c); wave k computes distinct-chain k (one scan) and
// distinct-class root k. Per-row lag-1 handoff via double-buffered LDS +
// one __syncthreads per row (parity proof: row h writes buf[h&1], read at
// h+1; previous read of buf[h&1] completed before barrier h-1). Product
// space (exp isomorphism): f=(1+relu(x))*mask, sentinel 0.0;
// out = exp(asum_t)*m_class - 1.
// ---------------------------------------------------------------------------
__global__ void fis_kernel(const float* __restrict__ x,
                           const float* __restrict__ alphas,
                           float* __restrict__ out, Plan pl) {
  __shared__ float lds[2 * CH_MAX * SLOTF];
  const int tid  = threadIdx.x;
  const int lane = tid & 63;
  const int wv   = tid >> 6;
  const int bc   = blockIdx.x;
  const int c    = bc & (CC - 1);
  const int b    = bc >> 4;

  const float* __restrict__ xp = x + (size_t)bc * (HH * WW);
  const int   w0   = lane * 4;
  const float mask = (w0 < WW) ? 1.f : 0.f;
  const float* __restrict__ cp = xp + ((w0 < WW) ? w0 : (WW - 4));

  for (int i = tid; i < 2 * CH_MAX * SLOTF; i += blockDim.x) lds[i] = 0.f;
  __syncthreads();

  const int  wi       = wv & 7;
  const bool hasChain = wv < pl.nchains;
  const bool hasRoot  = wv < pl.nroots;
  const int myeL  = __builtin_amdgcn_readfirstlane(pl.eL[wi]);
  const int mysrc = __builtin_amdgcn_readfirstlane(pl.src[wi]);
  const int myeS  = __builtin_amdgcn_readfirstlane(pl.eS[wi]);
  const int rRL   = __builtin_amdgcn_readfirstlane(pl.rRL[wi]);
  const int rNE   = __builtin_amdgcn_readfirstlane(pl.rN[wi] * pl.rExp[wi]);
  const int rIdx  = __builtin_amdgcn_readfirstlane(pl.rIdx[wi]);
  const int rT    = __builtin_amdgcn_readfirstlane(pl.rTrees[wi]);

  float4 pm = make_float4(0.f, 0.f, 0.f, 0.f), racc = pm;

  float4 X[4];
#pragma unroll
  for (int u = 0; u < 4; ++u) X[u] = *(const float4*)(cp + u * WW);

  for (int hb = 0; hb < HH; hb += 4) {
#pragma unroll
    for (int u = 0; u < 4; ++u) {
      const int h = hb + u;
      const float4 xr = X[u];
      const int nr = (h + 4 < HH) ? h + 4 : HH - 1;
      X[u] = *(const float4*)(cp + (size_t)nr * WW);

      const float* base = lds + ((h + 1) & 1) * (CH_MAX * SLOTF);  // row h-1

      // Issue all LDS source reads up front (hide ds_read latency).
      float4 sL4 = make_float4(0.f, 0.f, 0.f, 0.f), sS4 = sL4, sR4 = sL4;
      const bool needL = (hasChain && myeL > 0) || (hasRoot && rRL > 0);
      if (needL)                  sL4 = read_s(base, lane);
      if (hasChain && mysrc >= 0) sS4 = read_s(base + mysrc * SLOTF, lane);
      if (hasRoot && rNE > 0)     sR4 = read_s(base + rIdx * SLOTF, lane);

      float4 fv;
      fv.x = fmaf(fmaxf(xr.x, 0.f), mask, mask);
      fv.y = fmaf(fmaxf(xr.y, 0.f), mask, mask);
      fv.z = fmaf(fmaxf(xr.z, 0.f), mask, mask);
      fv.w = fmaf(fmaxf(xr.w, 0.f), mask, mask);

      if (hasRoot) {
        float4 r0 = fv;
        for (int j = 0; j < rRL; ++j) MUL4(r0, sL4);
        for (int j = 0; j < rNE; ++j) MUL4(r0, sR4);
        MAX4(racc, r0);
      }

      if (hasChain) {
        float4 v = fv;
        for (int j = 0; j < myeL; ++j) MUL4(v, sL4);
        for (int j = 0; j < myeS && mysrc >= 0; ++j) MUL4(v, sS4);

        float l0 = v.x;
        float l1 = fmaxf(l0, v.y);
        float l2 = fmaxf(l1, v.z);
        float q  = scan64(fmaxf(l2, v.w));
        float e  = wshr1(q);
        pm.x = fmaxf(fmaxf(e, l0), pm.x);
        pm.y = fmaxf(fmaxf(e, l1), pm.y);
        pm.z = fmaxf(fmaxf(e, l2), pm.z);
        pm.w = fmaxf(q, pm.w);
        *(float4*)(lds + (h & 1) * (CH_MAX * SLOTF) + wv * SLOTF + 4 + lane * 4) = pm;
      }

      __syncthreads();
    }
  }

  if (hasRoot) {
    float m = fmaxf(fmaxf(racc.x, racc.y), fmaxf(racc.z, racc.w));
#pragma unroll
    for (int d = 1; d < 64; d <<= 1) m = fmaxf(m, __shfl_xor(m, d));
    if (lane == 0) {
      for (int t = 0; t < NTREES; ++t) {
        if ((rT >> t) & 1) {
          float asum = 0.f;
          for (int i = 0; i < NNODES; ++i) asum += alphas[(t * NNODES + i) * CC + c];
          out[((size_t)b * NTREES + t) * CC + c] = expf(asum) * m - 1.f;
        }
      }
    }
  }
}

extern "C" void kernel_launch(void* const* d_in, const int* in_sizes, int n_in,
                              void* d_out, int out_size, void* d_ws, size_t ws_size,
                              hipStream_t stream) {
  const float* x      = (const float*)d_in[0];
  const float* alphas = (const float*)d_in[1];
  float* out          = (float*)d_out;

  Forest f;
  nprng::make_forest(f);  // deterministic; same every call (graph-capture safe)
  Plan pl;
  build_plan(f, pl);      // deterministic too

  dim3 grid(BB * CC);           // 128 blocks: one per (b,c) plane
  dim3 block(64 * pl.nw);       // one wave per distinct chain/root
  hipLaunchKernelGGL(fis_kernel, grid, block, 0, stream, x, alphas, out, pl);
}

// Round 10
// 120.086 us; speedup vs baseline: 1.3232x; 1.3232x over previous
//
#include <hip/hip_runtime.h>
#include <stdint.h>

#define NTREES 8
#define NNODES 5
#define CC 16
#define BB 8
#define HH 224
#define WW 224

#define DCH 4                       // rows per chunk
#define NCHUNK (HH / DCH)           // 56
#define EPOCHS (NCHUNK + 1)         // wave1 lags one chunk
#define ROWF 328                    // floats per published row: v4[256] + wcol[65] + pad
#define CHSTRIDE (3 * DCH * ROWF)   // per chain: 3 ring buffers x D rows

struct Forest { int par[NTREES * NNODES]; };
struct Cls { int v[NTREES]; };

// ---------------------------------------------------------------------------
// Host-side bit-exact reproduction of np.random.default_rng(0) forest
// (verified absmax 0.0 vs numpy in rounds 1-9 — do not touch).
// ---------------------------------------------------------------------------
namespace nprng {

struct Pcg {
  __uint128_t state, inc;
  int has_uint32;
  uint32_t uinteger;
};

static inline __uint128_t pcg_mult() {
  return (((__uint128_t)0x2360ED051FC65DA4ULL) << 64) | 0x4385DF649FCCF645ULL;
}

static inline void pcg_step(Pcg& s) { s.state = s.state * pcg_mult() + s.inc; }

static inline uint64_t pcg_next64(Pcg& s) {
  pcg_step(s);
  uint64_t xored = (uint64_t)(s.state >> 64) ^ (uint64_t)s.state;
  unsigned rot = (unsigned)(s.state >> 122);
  return (xored >> rot) | (xored << ((64u - rot) & 63u));
}

static inline uint32_t pcg_next32(Pcg& s) {
  if (s.has_uint32) { s.has_uint32 = 0; return s.uinteger; }
  uint64_t n = pcg_next64(s);
  s.has_uint32 = 1;
  s.uinteger = (uint32_t)(n >> 32);
  return (uint32_t)n;
}

static inline uint32_t lemire32(Pcg& s, uint32_t rng) {
  const uint32_t rng_excl = rng + 1u;
  uint64_t m = (uint64_t)pcg_next32(s) * (uint64_t)rng_excl;
  uint32_t leftover = (uint32_t)m;
  if (leftover < rng_excl) {
    const uint32_t threshold = (uint32_t)((0xFFFFFFFFu - rng) % rng_excl);
    while (leftover < threshold) {
      m = (uint64_t)pcg_next32(s) * (uint64_t)rng_excl;
      leftover = (uint32_t)m;
    }
  }
  return (uint32_t)(m >> 32);
}

static void make_forest(Forest& f) {
  const uint32_t INIT_A = 0x43b0d7e5u, MULT_A = 0x931e8875u;
  const uint32_t INIT_B = 0x8b51f9ddu, MULT_B = 0x58f38dedu;
  const uint32_t MIX_L  = 0xca01f9ddu, MIX_R  = 0x4973f715u;
  uint32_t pool[4];
  uint32_t hc = INIT_A;
  auto hashmix = [&](uint32_t v) -> uint32_t {
    v ^= hc; hc *= MULT_A; v *= hc; v ^= v >> 16; return v;
  };
  auto mix = [&](uint32_t x, uint32_t y) -> uint32_t {
    uint32_t r = MIX_L * x - MIX_R * y; r ^= r >> 16; return r;
  };
  pool[0] = hashmix(0u);
  for (int i = 1; i < 4; ++i) pool[i] = hashmix(0u);
  for (int is = 0; is < 4; ++is)
    for (int id = 0; id < 4; ++id)
      if (is != id) pool[id] = mix(pool[id], hashmix(pool[is]));
  uint32_t st32[8];
  uint32_t hb = INIT_B;
  for (int i = 0; i < 8; ++i) {
    uint32_t dv = pool[i & 3];
    dv ^= hb; hb *= MULT_B; dv *= hb; dv ^= dv >> 16;
    st32[i] = dv;
  }
  uint64_t w64[4];
  for (int i = 0; i < 4; ++i)
    w64[i] = (uint64_t)st32[2 * i] | ((uint64_t)st32[2 * i + 1] << 32);

  __uint128_t initstate = (((__uint128_t)w64[0]) << 64) | w64[1];
  __uint128_t initseq   = (((__uint128_t)w64[2]) << 64) | w64[3];
  Pcg s;
  s.state = 0; s.inc = (initseq << 1) | 1;
  pcg_step(s);
  s.state += initstate;
  pcg_step(s);
  s.has_uint32 = 0; s.uinteger = 0;

  for (int t = 0; t < NTREES; ++t) {
    f.par[t * NNODES + 0] = -1;
    for (int i = 1; i < NNODES; ++i) {
      uint32_t rng = (uint32_t)(i - 1);
      f.par[t * NNODES + i] = (rng == 0) ? 0 : (int)lemire32(s, rng);
    }
  }
}

}  // namespace nprng

// ---------------------------------------------------------------------------
// Tree-shape classification (verified absmax 0.0 in R8/R9).
// ---------------------------------------------------------------------------
static int classify_tree(const int* p) {
  int nch[NNODES] = {0, 0, 0, 0, 0};
  for (int i = 1; i < NNODES; ++i) nch[p[i]]++;
  int internals[3], nI = 0;
  for (int i = 1; i <= 3; ++i) if (nch[i] > 0) internals[nI++] = i;
  if (nI == 0) return 1;
  if (nI == 1) {
    int m = nch[internals[0]];
    return m == 1 ? 2 : (m == 2 ? 3 : 4);
  }
  if (nI == 2) {
    int i = internals[0], j = internals[1];
    if (p[j] == i) {
      if (nch[j] == 2) return 9;
      return (nch[i] - 1 == 1) ? 7 : 6;
    }
    return 5;
  }
  return 8;
}

// ---------------------------------------------------------------------------
// Class configs re-expressed by level (exponents identical to R8's verified
// Cfg<>): chain C1 = fv*sL^E1L; C2 = fv*sL^E2L*sC1; C3 = fv*sC2;
// root = fv*sL^RL*sC1^R1*sC2^R2*sC3^R3.
// ---------------------------------------------------------------------------
template <int CL> struct TC;
template <> struct TC<1> { static constexpr int H1=0,E1L=0,H2=0,E2L=0,H3=0,RL=4,R1=0,R2=0,R3=0; };
template <> struct TC<2> { static constexpr int H1=1,E1L=1,H2=0,E2L=0,H3=0,RL=2,R1=1,R2=0,R3=0; };
template <> struct TC<3> { static constexpr int H1=1,E1L=2,H2=0,E2L=0,H3=0,RL=1,R1=1,R2=0,R3=0; };
template <> struct TC<4> { static constexpr int H1=1,E1L=3,H2=0,E2L=0,H3=0,RL=0,R1=1,R2=0,R3=0; };
template <> struct TC<5> { static constexpr int H1=1,E1L=1,H2=0,E2L=0,H3=0,RL=0,R1=2,R2=0,R3=0; };
template <> struct TC<6> { static constexpr int H1=1,E1L=1,H2=1,E2L=0,H3=0,RL=1,R1=0,R2=1,R3=0; };
template <> struct TC<7> { static constexpr int H1=1,E1L=1,H2=1,E2L=1,H3=0,RL=0,R1=0,R2=1,R3=0; };
template <> struct TC<8> { static constexpr int H1=1,E1L=1,H2=1,E2L=0,H3=1,RL=0,R1=0,R2=0,R3=1; };
template <> struct TC<9> { static constexpr int H1=1,E1L=2,H2=1,E2L=0,H3=0,RL=0,R1=0,R2=1,R3=0; };

// ---------------------------------------------------------------------------
// DPP helpers (product space, max identity 0.0; patterns verified R4-R9).
// ---------------------------------------------------------------------------
__device__ __forceinline__ float wshr1(float t) {
  int r = __builtin_amdgcn_update_dpp(
      0, __builtin_bit_cast(int, t), 0x138, 0xf, 0xf, true);  // wave_shr:1
  return __builtin_bit_cast(float, r);
}

__device__ __forceinline__ float scan64(float q) {
  asm volatile(
      "s_nop 1\n\t"
      "v_max_f32_dpp %0, %0, %0 row_shr:1 row_mask:0xf bank_mask:0xf\n\t"
      "s_nop 1\n\t"
      "v_max_f32_dpp %0, %0, %0 row_shr:2 row_mask:0xf bank_mask:0xf\n\t"
      "s_nop 1\n\t"
      "v_max_f32_dpp %0, %0, %0 row_shr:4 row_mask:0xf bank_mask:0xf\n\t"
      "s_nop 1\n\t"
      "v_max_f32_dpp %0, %0, %0 row_shr:8 row_mask:0xf bank_mask:0xf\n\t"
      "s_nop 1\n\t"
      "v_max_f32_dpp %0, %0, %0 row_bcast:15 row_mask:0xa bank_mask:0xf\n\t"
      "s_nop 1\n\t"
      "v_max_f32_dpp %0, %0, %0 row_bcast:31 row_mask:0xc bank_mask:0xf\n\t"
      "s_nop 1"
      : "+v"(q));
  return q;
}

__device__ __forceinline__ void scan64x2(float& a, float& b) {
  asm volatile(
      "s_nop 1\n\t"
      "v_max_f32_dpp %0, %0, %0 row_shr:1 row_mask:0xf bank_mask:0xf\n\t"
      "v_max_f32_dpp %1, %1, %1 row_shr:1 row_mask:0xf bank_mask:0xf\n\t"
      "s_nop 0\n\t"
      "v_max_f32_dpp %0, %0, %0 row_shr:2 row_mask:0xf bank_mask:0xf\n\t"
      "v_max_f32_dpp %1, %1, %1 row_shr:2 row_mask:0xf bank_mask:0xf\n\t"
      "s_nop 0\n\t"
      "v_max_f32_dpp %0, %0, %0 row_shr:4 row_mask:0xf bank_mask:0xf\n\t"
      "v_max_f32_dpp %1, %1, %1 row_shr:4 row_mask:0xf bank_mask:0xf\n\t"
      "s_nop 0\n\t"
      "v_max_f32_dpp %0, %0, %0 row_shr:8 row_mask:0xf bank_mask:0xf\n\t"
      "v_max_f32_dpp %1, %1, %1 row_shr:8 row_mask:0xf bank_mask:0xf\n\t"
      "s_nop 0\n\t"
      "v_max_f32_dpp %0, %0, %0 row_bcast:15 row_mask:0xa bank_mask:0xf\n\t"
      "v_max_f32_dpp %1, %1, %1 row_bcast:15 row_mask:0xa bank_mask:0xf\n\t"
      "s_nop 0\n\t"
      "v_max_f32_dpp %0, %0, %0 row_bcast:31 row_mask:0xc bank_mask:0xf\n\t"
      "v_max_f32_dpp %1, %1, %1 row_bcast:31 row_mask:0xc bank_mask:0xf\n\t"
      "s_nop 1"
      : "+v"(a), "+v"(b));
}

#define MUL4(d, s) { (d).x *= (s).x; (d).y *= (s).y; (d).z *= (s).z; (d).w *= (s).w; }
#define MAX4(d, s) { (d).x = fmaxf((d).x,(s).x); (d).y = fmaxf((d).y,(s).y); \
                     (d).z = fmaxf((d).z,(s).z); (d).w = fmaxf((d).w,(s).w); }

template <int E>
__device__ __forceinline__ void powmul(float4& v, const float4& s) {
  if constexpr (E == 4) {
    float4 t = s; MUL4(t, t); MUL4(t, t); MUL4(v, t);
  } else {
    if constexpr (E >= 1) MUL4(v, s);
    if constexpr (E >= 2) MUL4(v, s);
    if constexpr (E >= 3) MUL4(v, s);
  }
}

// LDS row slot: v4[256] (float4/lane, 16B stride = 2-way = free) then
// wcol[65] at 256: wcol[0]=0 border (written only at init), wcol[1+l]=pm.w[l].
// Consumer reads wcol[lane] (stride-1, free) = pm.w[lane-1] -> shifted col.
__device__ __forceinline__ float4 read_s(const float* slot, int lane) {
  float4 pv = *(const float4*)(slot + 4 * lane);
  float  wb = slot[256 + lane];
  return make_float4(wb, pv.x, pv.y, pv.z);
}

__device__ __forceinline__ void publish(float* slot, int lane, const float4& pm) {
  *(float4*)(slot + 4 * lane) = pm;
  slot[256 + 1 + lane] = pm.w;
}

// ---------------------------------------------------------------------------
// One block per (tree,b,c), TWO waves:
//  wave0: chains L (+C1), publishes rows to LDS ring (3 chunk buffers x D=4).
//  wave1: chains C2/C3 + root, one chunk behind; reads L/C1 at row h-1 from
//         LDS; C2/C3/root own-state sources stay in registers.
// Race-freedom: epoch e -> wave0 writes buf e%3; wave1 reads (e-1)%3 and
// (e+1)%3 (the u==0 last-row-of-previous-chunk case) — disjoint mod 3,
// separated by the per-epoch barrier. Buf 2 zero-init = virtual row -1.
// Product space (exp isomorphism, verified R6-R9): f=(1+relu(x))*mask,
// sentinel 0.0, out = exp(asum)*m - 1.
// ---------------------------------------------------------------------------
template <int CL>
__device__ __forceinline__ void run_tree(const float* __restrict__ cp,
                                         float mask, float asum,
                                         float* __restrict__ outp,
                                         int wv, int lane, float* lds) {
  using F = TC<CL>;
  const float4 zero4 = make_float4(0.f, 0.f, 0.f, 0.f);

  if (wv == 0) {
    // ------------------- producer wave: L (+C1) -------------------
    float4 pm0 = zero4, pm1 = zero4;
    float4 X[DCH];
#pragma unroll
    for (int u = 0; u < DCH; ++u) X[u] = *(const float4*)(cp + u * WW);

    for (int e = 0; e < EPOCHS; ++e) {
      if (e < NCHUNK) {
        const int nb = (e + 1 < NCHUNK) ? e + 1 : NCHUNK - 1;
        float4 T[DCH];
#pragma unroll
        for (int u = 0; u < DCH; ++u)
          T[u] = *(const float4*)(cp + (size_t)(nb * DCH + u) * WW);

        float* wb0 = lds + ((e % 3) * DCH) * ROWF;
#pragma unroll
        for (int u = 0; u < DCH; ++u) {
          const float4 xr = X[u];
          float4 fv;
          fv.x = fmaf(fmaxf(xr.x, 0.f), mask, mask);
          fv.y = fmaf(fmaxf(xr.y, 0.f), mask, mask);
          fv.z = fmaf(fmaxf(xr.z, 0.f), mask, mask);
          fv.w = fmaf(fmaxf(xr.w, 0.f), mask, mask);

          float4 v1;
          if constexpr (F::H1) {
            float4 s0 = make_float4(wshr1(pm0.w), pm0.x, pm0.y, pm0.z);
            v1 = fv; powmul<F::E1L>(v1, s0);
          }

          float a0 = fv.x, a1 = fmaxf(a0, fv.y), a2 = fmaxf(a1, fv.z);
          float qa = fmaxf(a2, fv.w);
          float b0, b1, b2, qb;
          if constexpr (F::H1) {
            b0 = v1.x; b1 = fmaxf(b0, v1.y); b2 = fmaxf(b1, v1.z);
            qb = fmaxf(b2, v1.w);
            scan64x2(qa, qb);
          } else {
            qa = scan64(qa);
          }

          float ea = wshr1(qa);
          pm0.x = fmaxf(fmaxf(ea, a0), pm0.x);
          pm0.y = fmaxf(fmaxf(ea, a1), pm0.y);
          pm0.z = fmaxf(fmaxf(ea, a2), pm0.z);
          pm0.w = fmaxf(qa, pm0.w);
          publish(wb0 + u * ROWF, lane, pm0);

          if constexpr (F::H1) {
            float eb = wshr1(qb);
            pm1.x = fmaxf(fmaxf(eb, b0), pm1.x);
            pm1.y = fmaxf(fmaxf(eb, b1), pm1.y);
            pm1.z = fmaxf(fmaxf(eb, b2), pm1.z);
            pm1.w = fmaxf(qb, pm1.w);
            publish(wb0 + u * ROWF + CHSTRIDE, lane, pm1);
          }
        }
#pragma unroll
        for (int u = 0; u < DCH; ++u) X[u] = T[u];
      }
      __syncthreads();
    }
  } else {
    // ------------------- consumer wave: C2/C3 + root -------------------
    float4 pm2 = zero4, pm3 = zero4, racc = zero4;
    float4 X[DCH];
#pragma unroll
    for (int u = 0; u < DCH; ++u) X[u] = *(const float4*)(cp + u * WW);

    for (int e = 0; e < EPOCHS; ++e) {
      if (e >= 1) {
        const int c  = e - 1;
        const int nb = (c + 1 < NCHUNK) ? c + 1 : NCHUNK - 1;
        float4 T[DCH];
#pragma unroll
        for (int u = 0; u < DCH; ++u)
          T[u] = *(const float4*)(cp + (size_t)(nb * DCH + u) * WW);

#pragma unroll
        for (int u = 0; u < DCH; ++u) {
          const int buf = (u == 0) ? ((c + 2) % 3) : (c % 3);
          const int uu  = (u == 0) ? (DCH - 1) : (u - 1);
          const float* sp = lds + (buf * DCH + uu) * ROWF;
          float4 sL  = read_s(sp, lane);
          float4 sC1 = zero4;
          if constexpr (F::H1) sC1 = read_s(sp + CHSTRIDE, lane);

          const float4 xr = X[u];
          float4 fv;
          fv.x = fmaf(fmaxf(xr.x, 0.f), mask, mask);
          fv.y = fmaf(fmaxf(xr.y, 0.f), mask, mask);
          fv.z = fmaf(fmaxf(xr.z, 0.f), mask, mask);
          fv.w = fmaf(fmaxf(xr.w, 0.f), mask, mask);

          float4 s2, s3;
          if constexpr (F::H2) s2 = make_float4(wshr1(pm2.w), pm2.x, pm2.y, pm2.z);
          if constexpr (F::H3) s3 = make_float4(wshr1(pm3.w), pm3.x, pm3.y, pm3.z);

          // root (all sources at row h-1)
          float4 r0 = fv;
          powmul<F::RL>(r0, sL);
          if constexpr (F::R1 > 0) powmul<F::R1>(r0, sC1);
          if constexpr (F::R2 > 0) powmul<F::R2>(r0, s2);
          if constexpr (F::R3 > 0) powmul<F::R3>(r0, s3);
          MAX4(racc, r0);

          if constexpr (F::H2) {
            float4 v2 = fv;
            if constexpr (F::E2L > 0) MUL4(v2, sL);
            MUL4(v2, sC1);
            float a0 = v2.x, a1 = fmaxf(a0, v2.y), a2 = fmaxf(a1, v2.z);
            float qa = fmaxf(a2, v2.w);
            if constexpr (F::H3) {
              float4 v3 = fv; MUL4(v3, s2);
              float b0 = v3.x, b1 = fmaxf(b0, v3.y), b2 = fmaxf(b1, v3.z);
              float qb = fmaxf(b2, v3.w);
              scan64x2(qa, qb);
              float eb = wshr1(qb);
              pm3.x = fmaxf(fmaxf(eb, b0), pm3.x);
              pm3.y = fmaxf(fmaxf(eb, b1), pm3.y);
              pm3.z = fmaxf(fmaxf(eb, b2), pm3.z);
              pm3.w = fmaxf(qb, pm3.w);
            } else {
              qa = scan64(qa);
            }
            float ea = wshr1(qa);
            pm2.x = fmaxf(fmaxf(ea, a0), pm2.x);
            pm2.y = fmaxf(fmaxf(ea, a1), pm2.y);
            pm2.z = fmaxf(fmaxf(ea, a2), pm2.z);
            pm2.w = fmaxf(qa, pm2.w);
          }
        }
#pragma unroll
        for (int u = 0; u < DCH; ++u) X[u] = T[u];
      }
      __syncthreads();
    }

    float m = fmaxf(fmaxf(racc.x, racc.y), fmaxf(racc.z, racc.w));
#pragma unroll
    for (int d = 1; d < 64; d <<= 1) m = fmaxf(m, __shfl_xor(m, d));
    if (lane == 0) *outp = expf(asum) * m - 1.f;
  }
}

__global__ __launch_bounds__(128) void fis_kernel(const float* __restrict__ x,
                                                  const float* __restrict__ alphas,
                                                  float* __restrict__ out,
                                                  Cls cls) {
  __shared__ float lds[2 * CHSTRIDE];
  const int tid  = threadIdx.x;
  const int lane = tid & 63;
  const int wv   = tid >> 6;
  const int blk  = blockIdx.x;
  const int t    = blk >> 7;     // blocks 128 apart share x-plane -> same XCD
  const int bc   = blk & 127;
  const int c    = bc & (CC - 1);
  const int b    = bc >> 4;

  const float* __restrict__ xp = x + (size_t)bc * (HH * WW);

  float asum = 0.f;
#pragma unroll
  for (int i = 0; i < NNODES; ++i) asum += alphas[(t * NNODES + i) * CC + c];

  const int   w0   = lane * 4;
  const float mask = (w0 < WW) ? 1.0f : 0.0f;
  const float* __restrict__ cp = xp + ((w0 < WW) ? w0 : (WW - 4));
  float* outp = out + ((size_t)b * NTREES + t) * CC + c;

  // Zero LDS (buf 2 = virtual row -1 must be 0; wcol[0] borders stay 0).
  for (int i = tid; i < 2 * CHSTRIDE; i += 128) lds[i] = 0.f;
  __syncthreads();

  switch (cls.v[t]) {
    case 1: run_tree<1>(cp, mask, asum, outp, wv, lane, lds); break;
    case 2: run_tree<2>(cp, mask, asum, outp, wv, lane, lds); break;
    case 3: run_tree<3>(cp, mask, asum, outp, wv, lane, lds); break;
    case 4: run_tree<4>(cp, mask, asum, outp, wv, lane, lds); break;
    case 5: run_tree<5>(cp, mask, asum, outp, wv, lane, lds); break;
    case 6: run_tree<6>(cp, mask, asum, outp, wv, lane, lds); break;
    case 7: run_tree<7>(cp, mask, asum, outp, wv, lane, lds); break;
    case 8: run_tree<8>(cp, mask, asum, outp, wv, lane, lds); break;
    case 9: run_tree<9>(cp, mask, asum, outp, wv, lane, lds); break;
    default: break;
  }
}

extern "C" void kernel_launch(void* const* d_in, const int* in_sizes, int n_in,
                              void* d_out, int out_size, void* d_ws, size_t ws_size,
                              hipStream_t stream) {
  const float* x      = (const float*)d_in[0];
  const float* alphas = (const float*)d_in[1];
  float* out          = (float*)d_out;

  Forest f;
  nprng::make_forest(f);  // deterministic; same every call (graph-capture safe)

  Cls cls;
  for (int t = 0; t < NTREES; ++t)
    cls.v[t] = classify_tree(&f.par[t * NNODES]);

  dim3 grid(BB * CC * NTREES);  // 1024 blocks x 2 waves = 2 waves/SIMD
  dim3 block(128);
  hipLaunchKernelGGL(fis_kernel, grid, block, 0, stream, x, alphas, out, cls);
}

// Round 11
// 98.314 us; speedup vs baseline: 1.6162x; 1.2214x over previous
//
#include <hip/hip_runtime.h>
#include <stdint.h>

#define NTREES 8
#define NNODES 5
#define CC 16
#define BB 8
#define HH 224
#define WW 224
#define NBAND 28          // 224 / 8 rows per band

struct Forest { int par[NTREES * NNODES]; };
struct Cls { int v[NTREES]; };

// ---------------------------------------------------------------------------
// Host-side bit-exact reproduction of np.random.default_rng(0) forest
// (verified absmax 0.0 vs numpy in rounds 1-10 — do not touch).
// ---------------------------------------------------------------------------
namespace nprng {

struct Pcg {
  __uint128_t state, inc;
  int has_uint32;
  uint32_t uinteger;
};

static inline __uint128_t pcg_mult() {
  return (((__uint128_t)0x2360ED051FC65DA4ULL) << 64) | 0x4385DF649FCCF645ULL;
}

static inline void pcg_step(Pcg& s) { s.state = s.state * pcg_mult() + s.inc; }

static inline uint64_t pcg_next64(Pcg& s) {
  pcg_step(s);
  uint64_t xored = (uint64_t)(s.state >> 64) ^ (uint64_t)s.state;
  unsigned rot = (unsigned)(s.state >> 122);
  return (xored >> rot) | (xored << ((64u - rot) & 63u));
}

static inline uint32_t pcg_next32(Pcg& s) {
  if (s.has_uint32) { s.has_uint32 = 0; return s.uinteger; }
  uint64_t n = pcg_next64(s);
  s.has_uint32 = 1;
  s.uinteger = (uint32_t)(n >> 32);
  return (uint32_t)n;
}

static inline uint32_t lemire32(Pcg& s, uint32_t rng) {
  const uint32_t rng_excl = rng + 1u;
  uint64_t m = (uint64_t)pcg_next32(s) * (uint64_t)rng_excl;
  uint32_t leftover = (uint32_t)m;
  if (leftover < rng_excl) {
    const uint32_t threshold = (uint32_t)((0xFFFFFFFFu - rng) % rng_excl);
    while (leftover < threshold) {
      m = (uint64_t)pcg_next32(s) * (uint64_t)rng_excl;
      leftover = (uint32_t)m;
    }
  }
  return (uint32_t)(m >> 32);
}

static void make_forest(Forest& f) {
  const uint32_t INIT_A = 0x43b0d7e5u, MULT_A = 0x931e8875u;
  const uint32_t INIT_B = 0x8b51f9ddu, MULT_B = 0x58f38dedu;
  const uint32_t MIX_L  = 0xca01f9ddu, MIX_R  = 0x4973f715u;
  uint32_t pool[4];
  uint32_t hc = INIT_A;
  auto hashmix = [&](uint32_t v) -> uint32_t {
    v ^= hc; hc *= MULT_A; v *= hc; v ^= v >> 16; return v;
  };
  auto mix = [&](uint32_t x, uint32_t y) -> uint32_t {
    uint32_t r = MIX_L * x - MIX_R * y; r ^= r >> 16; return r;
  };
  pool[0] = hashmix(0u);
  for (int i = 1; i < 4; ++i) pool[i] = hashmix(0u);
  for (int is = 0; is < 4; ++is)
    for (int id = 0; id < 4; ++id)
      if (is != id) pool[id] = mix(pool[id], hashmix(pool[is]));
  uint32_t st32[8];
  uint32_t hb = INIT_B;
  for (int i = 0; i < 8; ++i) {
    uint32_t dv = pool[i & 3];
    dv ^= hb; hb *= MULT_B; dv *= hb; dv ^= dv >> 16;
    st32[i] = dv;
  }
  uint64_t w64[4];
  for (int i = 0; i < 4; ++i)
    w64[i] = (uint64_t)st32[2 * i] | ((uint64_t)st32[2 * i + 1] << 32);

  __uint128_t initstate = (((__uint128_t)w64[0]) << 64) | w64[1];
  __uint128_t initseq   = (((__uint128_t)w64[2]) << 64) | w64[3];
  Pcg s;
  s.state = 0; s.inc = (initseq << 1) | 1;
  pcg_step(s);
  s.state += initstate;
  pcg_step(s);
  s.has_uint32 = 0; s.uinteger = 0;

  for (int t = 0; t < NTREES; ++t) {
    f.par[t * NNODES + 0] = -1;
    for (int i = 1; i < NNODES; ++i) {
      uint32_t rng = (uint32_t)(i - 1);
      f.par[t * NNODES + i] = (rng == 0) ? 0 : (int)lemire32(s, rng);
    }
  }
}

}  // namespace nprng

// ---------------------------------------------------------------------------
// Tree-shape classification + level-form class configs (verified absmax 0.0
// in R8/R10): chain C1 = fv*sL^E1L; C2 = fv*sL^E2L*sC1; C3 = fv*sC2;
// root = fv*sL^RL*sC1^R1*sC2^R2*sC3^R3.
// ---------------------------------------------------------------------------
static int classify_tree(const int* p) {
  int nch[NNODES] = {0, 0, 0, 0, 0};
  for (int i = 1; i < NNODES; ++i) nch[p[i]]++;
  int internals[3], nI = 0;
  for (int i = 1; i <= 3; ++i) if (nch[i] > 0) internals[nI++] = i;
  if (nI == 0) return 1;
  if (nI == 1) {
    int m = nch[internals[0]];
    return m == 1 ? 2 : (m == 2 ? 3 : 4);
  }
  if (nI == 2) {
    int i = internals[0], j = internals[1];
    if (p[j] == i) {
      if (nch[j] == 2) return 9;
      return (nch[i] - 1 == 1) ? 7 : 6;
    }
    return 5;
  }
  return 8;
}

template <int CL> struct TC;
template <> struct TC<1> { static constexpr int H1=0,E1L=0,H2=0,E2L=0,H3=0,RL=4,R1=0,R2=0,R3=0; };
template <> struct TC<2> { static constexpr int H1=1,E1L=1,H2=0,E2L=0,H3=0,RL=2,R1=1,R2=0,R3=0; };
template <> struct TC<3> { static constexpr int H1=1,E1L=2,H2=0,E2L=0,H3=0,RL=1,R1=1,R2=0,R3=0; };
template <> struct TC<4> { static constexpr int H1=1,E1L=3,H2=0,E2L=0,H3=0,RL=0,R1=1,R2=0,R3=0; };
template <> struct TC<5> { static constexpr int H1=1,E1L=1,H2=0,E2L=0,H3=0,RL=0,R1=2,R2=0,R3=0; };
template <> struct TC<6> { static constexpr int H1=1,E1L=1,H2=1,E2L=0,H3=0,RL=1,R1=0,R2=1,R3=0; };
template <> struct TC<7> { static constexpr int H1=1,E1L=1,H2=1,E2L=1,H3=0,RL=0,R1=0,R2=1,R3=0; };
template <> struct TC<8> { static constexpr int H1=1,E1L=1,H2=1,E2L=0,H3=1,RL=0,R1=0,R2=0,R3=1; };
template <> struct TC<9> { static constexpr int H1=1,E1L=2,H2=1,E2L=0,H3=0,RL=0,R1=0,R2=1,R3=0; };

// ---------------------------------------------------------------------------
// DPP helpers (product space, max identity 0.0; patterns verified R4-R10).
// wshr1: single v_mov_b32_dpp wave_shr:1, 0 into lane 0 (border sentinel).
// SCAN8: 8 INDEPENDENT inclusive 64-lane max-scans, stage-major interleaved
// (dependent same-register DPPs are 8 insts apart -> no internal nops).
// Leading/trailing s_nop 1 cover VALU<->DPP hazards at the asm boundary.
// ---------------------------------------------------------------------------
__device__ __forceinline__ float wshr1(float t) {
  int r = __builtin_amdgcn_update_dpp(
      0, __builtin_bit_cast(int, t), 0x138, 0xf, 0xf, true);  // wave_shr:1
  return __builtin_bit_cast(float, r);
}

#define S8STAGE(MODS) \
  "v_max_f32_dpp %0, %0, %0 " MODS "\n\t" \
  "v_max_f32_dpp %1, %1, %1 " MODS "\n\t" \
  "v_max_f32_dpp %2, %2, %2 " MODS "\n\t" \
  "v_max_f32_dpp %3, %3, %3 " MODS "\n\t" \
  "v_max_f32_dpp %4, %4, %4 " MODS "\n\t" \
  "v_max_f32_dpp %5, %5, %5 " MODS "\n\t" \
  "v_max_f32_dpp %6, %6, %6 " MODS "\n\t" \
  "v_max_f32_dpp %7, %7, %7 " MODS "\n\t"

#define SCAN8(q)                                              \
  asm volatile(                                               \
      "s_nop 1\n\t"                                           \
      S8STAGE("row_shr:1 row_mask:0xf bank_mask:0xf")         \
      S8STAGE("row_shr:2 row_mask:0xf bank_mask:0xf")         \
      S8STAGE("row_shr:4 row_mask:0xf bank_mask:0xf")         \
      S8STAGE("row_shr:8 row_mask:0xf bank_mask:0xf")         \
      S8STAGE("row_bcast:15 row_mask:0xa bank_mask:0xf")      \
      S8STAGE("row_bcast:31 row_mask:0xc bank_mask:0xf")      \
      "s_nop 1"                                               \
      : "+v"(q[0]), "+v"(q[1]), "+v"(q[2]), "+v"(q[3]),       \
        "+v"(q[4]), "+v"(q[5]), "+v"(q[6]), "+v"(q[7]))

#define MUL4(d, s) { (d).x *= (s).x; (d).y *= (s).y; (d).z *= (s).z; (d).w *= (s).w; }
#define MAX4(d, s) { (d).x = fmaxf((d).x,(s).x); (d).y = fmaxf((d).y,(s).y); \
                     (d).z = fmaxf((d).z,(s).z); (d).w = fmaxf((d).w,(s).w); }

template <int E>
__device__ __forceinline__ void powmul(float4& v, const float4& s) {
  if constexpr (E == 4) {
    float4 t = s; MUL4(t, t); MUL4(t, t); MUL4(v, t);
  } else {
    if constexpr (E >= 1) MUL4(v, s);
    if constexpr (E >= 2) MUL4(v, s);
    if constexpr (E >= 3) MUL4(v, s);
  }
}

// s(h) = shift of M(h-1): row -1 comes from the band carry.
__device__ __forceinline__ float4 shiftrow(const float4* M, int u, const float4& carry) {
  float4 p = (u == 0) ? carry : M[u - 1];
  return make_float4(wshr1(p.w), p.x, p.y, p.z);
}

// ---------------------------------------------------------------------------
// Band-parallel level-pass DP. One wave per (tree,b,c). Product space
// (exp isomorphism, verified R6-R10): f=(1+relu(x))*mask, sentinel 0.0,
// out = exp(asum)*m - 1.
//
// KEY RESTRUCTURE vs R8: rows are processed in bands of 8, LEVEL by LEVEL.
// Within a band, level l's row values v_l(h) = fv(h)*shift(M_{l-1}(h-1))
// depend only on the PREVIOUS level's M (children are strictly lower levels)
// => the 8 prefix scans of a pass are mutually independent => SCAN8 is
// issue-bound (stage-major, deps 8 insts apart), breaking R8's row-serial
// DPP-latency chain (~460 cyc/row -> ~120). Column direction is an
// in-register running max with a per-chain band carry (exact by max
// associativity; same operand values as R8 => bit-exact).
// ---------------------------------------------------------------------------
template <int CL>
__device__ __forceinline__ void run_tree(const float* __restrict__ cp,
                                         float mask, float asum,
                                         float* __restrict__ outp, int lane) {
  using F = TC<CL>;
  const float4 z4 = make_float4(0.f, 0.f, 0.f, 0.f);
  float4 cL = z4, c1 = z4, c2 = z4, c3 = z4, racc = z4;

  float4 X[8];
#pragma unroll
  for (int u = 0; u < 8; ++u) X[u] = *(const float4*)(cp + u * WW);

#pragma unroll 1
  for (int band = 0; band < NBAND; ++band) {
    const int nb = (band + 1 < NBAND) ? band + 1 : NBAND - 1;
    float4 T[8];
#pragma unroll
    for (int u = 0; u < 8; ++u)
      T[u] = *(const float4*)(cp + (size_t)(nb * 8 + u) * WW);

    float4 fv[8];
#pragma unroll
    for (int u = 0; u < 8; ++u) {
      const float4 xr = X[u];
      fv[u].x = fmaf(fmaxf(xr.x, 0.f), mask, mask);
      fv[u].y = fmaf(fmaxf(xr.y, 0.f), mask, mask);
      fv[u].z = fmaf(fmaxf(xr.z, 0.f), mask, mask);
      fv[u].w = fmaf(fmaxf(xr.w, 0.f), mask, mask);
    }

    float4 ML[8], M1[8], M2[8], M3[8];

    // ---- pass 0: leaf chain (v = fv) ----
    {
      float l0[8], l1[8], l2[8], q[8];
#pragma unroll
      for (int u = 0; u < 8; ++u) {
        l0[u] = fv[u].x;
        l1[u] = fmaxf(l0[u], fv[u].y);
        l2[u] = fmaxf(l1[u], fv[u].z);
        q[u]  = fmaxf(l2[u], fv[u].w);
      }
      SCAN8(q);
      float4 run = cL;
#pragma unroll
      for (int u = 0; u < 8; ++u) {
        float e = wshr1(q[u]);
        run.x = fmaxf(run.x, fmaxf(e, l0[u]));
        run.y = fmaxf(run.y, fmaxf(e, l1[u]));
        run.z = fmaxf(run.z, fmaxf(e, l2[u]));
        run.w = fmaxf(run.w, q[u]);
        ML[u] = run;
      }
    }

    // ---- pass 1: C1 = fv * sL^E1L ----
    if constexpr (F::H1) {
      float l0[8], l1[8], l2[8], q[8];
#pragma unroll
      for (int u = 0; u < 8; ++u) {
        float4 v = fv[u];
        powmul<F::E1L>(v, shiftrow(ML, u, cL));
        l0[u] = v.x;
        l1[u] = fmaxf(l0[u], v.y);
        l2[u] = fmaxf(l1[u], v.z);
        q[u]  = fmaxf(l2[u], v.w);
      }
      SCAN8(q);
      float4 run = c1;
#pragma unroll
      for (int u = 0; u < 8; ++u) {
        float e = wshr1(q[u]);
        run.x = fmaxf(run.x, fmaxf(e, l0[u]));
        run.y = fmaxf(run.y, fmaxf(e, l1[u]));
        run.z = fmaxf(run.z, fmaxf(e, l2[u]));
        run.w = fmaxf(run.w, q[u]);
        M1[u] = run;
      }
    }

    // ---- pass 2: C2 = fv * sL^E2L * sC1 ----
    if constexpr (F::H2) {
      float l0[8], l1[8], l2[8], q[8];
#pragma unroll
      for (int u = 0; u < 8; ++u) {
        float4 v = fv[u];
        if constexpr (F::E2L > 0) powmul<F::E2L>(v, shiftrow(ML, u, cL));
        { float4 s1 = shiftrow(M1, u, c1); MUL4(v, s1); }
        l0[u] = v.x;
        l1[u] = fmaxf(l0[u], v.y);
        l2[u] = fmaxf(l1[u], v.z);
        q[u]  = fmaxf(l2[u], v.w);
      }
      SCAN8(q);
      float4 run = c2;
#pragma unroll
      for (int u = 0; u < 8; ++u) {
        float e = wshr1(q[u]);
        run.x = fmaxf(run.x, fmaxf(e, l0[u]));
        run.y = fmaxf(run.y, fmaxf(e, l1[u]));
        run.z = fmaxf(run.z, fmaxf(e, l2[u]));
        run.w = fmaxf(run.w, q[u]);
        M2[u] = run;
      }
    }

    // ---- pass 3: C3 = fv * sC2 ----
    if constexpr (F::H3) {
      float l0[8], l1[8], l2[8], q[8];
#pragma unroll
      for (int u = 0; u < 8; ++u) {
        float4 v = fv[u];
        { float4 s2 = shiftrow(M2, u, c2); MUL4(v, s2); }
        l0[u] = v.x;
        l1[u] = fmaxf(l0[u], v.y);
        l2[u] = fmaxf(l1[u], v.z);
        q[u]  = fmaxf(l2[u], v.w);
      }
      SCAN8(q);
      float4 run = c3;
#pragma unroll
      for (int u = 0; u < 8; ++u) {
        float e = wshr1(q[u]);
        run.x = fmaxf(run.x, fmaxf(e, l0[u]));
        run.y = fmaxf(run.y, fmaxf(e, l1[u]));
        run.z = fmaxf(run.z, fmaxf(e, l2[u]));
        run.w = fmaxf(run.w, q[u]);
        M3[u] = run;
      }
    }

    // ---- root pass: r(h) = fv * sL^RL * sC1^R1 * sC2^R2 * sC3^R3 ----
#pragma unroll
    for (int u = 0; u < 8; ++u) {
      float4 r = fv[u];
      if constexpr (F::RL > 0) powmul<F::RL>(r, shiftrow(ML, u, cL));
      if constexpr (F::R1 > 0) powmul<F::R1>(r, shiftrow(M1, u, c1));
      if constexpr (F::R2 > 0) powmul<F::R2>(r, shiftrow(M2, u, c2));
      if constexpr (F::R3 > 0) powmul<F::R3>(r, shiftrow(M3, u, c3));
      MAX4(racc, r);
    }

    // band carries (updated only after all uses of the old values)
    cL = ML[7];
    if constexpr (F::H1) c1 = M1[7];
    if constexpr (F::H2) c2 = M2[7];
    if constexpr (F::H3) c3 = M3[7];

#pragma unroll
    for (int u = 0; u < 8; ++u) X[u] = T[u];
  }

  float m = fmaxf(fmaxf(racc.x, racc.y), fmaxf(racc.z, racc.w));
#pragma unroll
  for (int d = 1; d < 64; d <<= 1) m = fmaxf(m, __shfl_xor(m, d));
  if (lane == 0) *outp = expf(asum) * m - 1.f;
}

__global__ __launch_bounds__(64) void fis_kernel(const float* __restrict__ x,
                                                 const float* __restrict__ alphas,
                                                 float* __restrict__ out,
                                                 Cls cls) {
  const int lane = threadIdx.x;
  const int blk  = blockIdx.x;
  const int t    = blk >> 7;     // blocks 128 apart share x-plane -> same XCD
  const int bc   = blk & 127;
  const int c    = bc & (CC - 1);
  const int b    = bc >> 4;

  const float* __restrict__ xp = x + (size_t)bc * (HH * WW);

  float asum = 0.f;
#pragma unroll
  for (int i = 0; i < NNODES; ++i) asum += alphas[(t * NNODES + i) * CC + c];

  const int   w0   = lane * 4;
  const float mask = (w0 < WW) ? 1.0f : 0.0f;
  const float* __restrict__ cp = xp + ((w0 < WW) ? w0 : (WW - 4));
  float* outp = out + ((size_t)b * NTREES + t) * CC + c;

  switch (cls.v[t]) {
    case 1: run_tree<1>(cp, mask, asum, outp, lane); break;
    case 2: run_tree<2>(cp, mask, asum, outp, lane); break;
    case 3: run_tree<3>(cp, mask, asum, outp, lane); break;
    case 4: run_tree<4>(cp, mask, asum, outp, lane); break;
    case 5: run_tree<5>(cp, mask, asum, outp, lane); break;
    case 6: run_tree<6>(cp, mask, asum, outp, lane); break;
    case 7: run_tree<7>(cp, mask, asum, outp, lane); break;
    case 8: run_tree<8>(cp, mask, asum, outp, lane); break;
    case 9: run_tree<9>(cp, mask, asum, outp, lane); break;
    default: break;
  }
}

extern "C" void kernel_launch(void* const* d_in, const int* in_sizes, int n_in,
                              void* d_out, int out_size, void* d_ws, size_t ws_size,
                              hipStream_t stream) {
  const float* x      = (const float*)d_in[0];
  const float* alphas = (const float*)d_in[1];
  float* out          = (float*)d_out;

  Forest f;
  nprng::make_forest(f);  // deterministic; same every call (graph-capture safe)

  Cls cls;
  for (int t = 0; t < NTREES; ++t)
    cls.v[t] = classify_tree(&f.par[t * NNODES]);

  dim3 grid(BB * CC * NTREES);  // 1024 single-wave blocks
  dim3 block(64);
  hipLaunchKernelGGL(fis_kernel, grid, block, 0, stream, x, alphas, out, cls);
}